// Round 9
// baseline (13777.286 us; speedup 1.0000x reference)
//
#include <hip/hip_runtime.h>
#include <cstdint>
#include <cstddef>

// Autoregressive LSTM cell with softmax feedback. B=256, T=512, D=512, N=64.
// R9 = R8 with ONE bug fixed: the W_lin LDS staging loop copied only 2048 of 4096
// float4 units (i<4 instead of i<8), leaving y-columns 32..63 as poisoned LDS ->
// NaN logits. Everything else unchanged from R8:
//  - Single flag barrier per step (timeout->abort, never hangs); next-step x-GEMM
//    prefetch runs in the barrier's propagation shadow.
//  - Full hi/lo (effective-fp32) numerics on every recurrence-path operand
//    (R7 lesson: the 512-step feedback loop amplifies per-step error ~150x).
//  - y computed redundantly per block via MFMA y-GEMM, W_lin hi/lo frags in LDS
//    (128KB); gates weights stream from GLOBAL (block-private 136KB slice, L2-warm:
//    16 blocks/XCD x 136KB = 2.2MB < 4MB, never invalidated by the relaxed protocol).
//  - h = hi/lo u32/elem row-major, u64 LLC atomic loads / u32 atomic stores.

typedef _Float16 f16x8 __attribute__((ext_vector_type(8)));
typedef float f32x4 __attribute__((ext_vector_type(4)));
typedef unsigned long long u64;

#define MFMA16(a, b, c_) __builtin_amdgcn_mfma_f32_16x16x32_f16((a), (b), (c_), 0, 0, 0)
#define AGT __HIP_MEMORY_SCOPE_AGENT
#define RLX __ATOMIC_RELAXED

#define FLAG_INTS (256 * 64 + 64)  // 256 padded flag slots + abort word
#define HS2_U32 131072             // per h buffer: 256 rows * 512 u32 (hi|lo<<16)

static __device__ __forceinline__ unsigned short f2b(_Float16 h) {
  return __builtin_bit_cast(unsigned short, h);
}
static __device__ __forceinline__ _Float16 b2f(unsigned short s) {
  return __builtin_bit_cast(_Float16, s);
}

__device__ __forceinline__ void cvt8(const float4 a, const float4 b, f16x8& hi, f16x8& lo) {
  float v[8] = {a.x, a.y, a.z, a.w, b.x, b.y, b.z, b.w};
#pragma unroll
  for (int j = 0; j < 8; ++j) {
    _Float16 h = (_Float16)v[j];
    hi[j] = h;
    lo[j] = (_Float16)(v[j] - (float)h);
  }
}

// ---------------------------------------------------------------------------
// prep. Slot map sigma(q,j)=4q+(j&3)+16*(j>>2) on A and B frags (R2-R6 verified).
// wf (gates B-frags, stays in GLOBAL): ct=cb*2+cth, col(l15)=(l15>>2)*512+cb*8+cth*4+(l15&3).
// wlf_hi/wlf_lo (y-GEMM B-frags -> LDS): [(ct*16+ki)*64+l]*8, col=ct*16+(l&15).
// hs2: u32 row-major [2][256][512], value = f16hi | f16lo<<16; buffer0 = init_h.
// ---------------------------------------------------------------------------
template <bool XPRE>
__global__ void prep_kernel(const float* __restrict__ x, const float* __restrict__ init_h,
                            const float* __restrict__ W_ih, const float* __restrict__ b_ih,
                            const float* __restrict__ W_hh, const float* __restrict__ b_hh,
                            const float* __restrict__ W_lin, _Float16* __restrict__ xs,
                            _Float16* __restrict__ wf, _Float16* __restrict__ wlf_hi,
                            _Float16* __restrict__ wlf_lo, unsigned int* __restrict__ hs2,
                            float* __restrict__ bias, int* __restrict__ flags) {
  const long NX = XPRE ? 256L * 512 * 16 * 4 : 0;
  const int NWF = 128 * 34 * 64;
  const int NWLF = 4 * 16 * 64;
  const int NH2 = 256 * 128;
  long tid = (long)blockIdx.x * 256 + threadIdx.x;

  if (XPRE && tid < NX) {
    int q = tid & 3, ki = (tid >> 2) & 15, t = (tid >> 6) & 511;
    int row = (int)(tid >> 15);
    const float* s = x + (((size_t)row * 512 + t) * 512 + ki * 32 + 4 * q);
    float4 a = *(const float4*)s, b = *(const float4*)(s + 16);
    f16x8 hi, lo;
    cvt8(a, b, hi, lo);
    _Float16* d = xs + ((((size_t)row * 512 + t) * 16 + ki) * 64 + q * 16);
    *(f16x8*)d = hi;
    *(f16x8*)(d + 8) = lo;
    return;
  }
  long u = tid - NX;
  if (u >= 0 && u < NWF) {
    int l = (int)(u & 63);
    int u2 = (int)(u >> 6);
    int ki = u2 % 34, ct = u2 / 34;
    int cb = ct >> 1, cth = ct & 1;
    int l15 = l & 15;
    int col = (l15 >> 2) * 512 + cb * 8 + cth * 4 + (l15 & 3);
    int k = ki * 32 + 4 * (l >> 4);
    float4 a, b;
    if (k < 512) {
      const float* p = W_ih + (size_t)col * 576;
      a = *(const float4*)(p + k);
      b = *(const float4*)(p + k + 16);
    } else if (k < 1024) {
      const float* p = W_hh + (size_t)col * 512;
      a = *(const float4*)(p + k - 512);
      b = *(const float4*)(p + k - 512 + 16);
    } else {
      const float* p = W_ih + (size_t)col * 576 + 512;
      a = *(const float4*)(p + k - 1024);
      b = *(const float4*)(p + k - 1024 + 16);
    }
    f16x8 hi, lo;
    cvt8(a, b, hi, lo);
    _Float16* d = wf + (((size_t)ct * 34 + ki) * 64 + l) * 16;
    *(f16x8*)d = hi;
    *(f16x8*)(d + 8) = lo;
    return;
  }
  u -= NWF;
  if (u >= 0 && u < NWLF) {
    int l = (int)(u & 63);
    int u2 = (int)(u >> 6);
    int ki = u2 & 15, ct = u2 >> 4;
    int col = ct * 16 + (l & 15);
    int k = ki * 32 + 4 * (l >> 4);
    const float* p = W_lin + (size_t)col * 512;
    float4 a = *(const float4*)(p + k), b = *(const float4*)(p + k + 16);
    f16x8 hi, lo;
    cvt8(a, b, hi, lo);
    _Float16* dh = wlf_hi + ((size_t)(ct * 16 + ki) * 64 + l) * 8;
    _Float16* dl = wlf_lo + ((size_t)(ct * 16 + ki) * 64 + l) * 8;
    *(f16x8*)dh = hi;
    *(f16x8*)dl = lo;
    return;
  }
  u -= NWLF;
  if (u >= 0 && u < NH2) {
    int g4 = (int)(u & 127), row = (int)(u >> 7);
    const float* s = init_h + (size_t)row * 512 + g4 * 4;
    float4 a = *(const float4*)s;
    float v[4] = {a.x, a.y, a.z, a.w};
    unsigned int* d = hs2 + (size_t)row * 512 + g4 * 4;  // buffer 0
#pragma unroll
    for (int j = 0; j < 4; ++j) {
      _Float16 hh = (_Float16)v[j];
      _Float16 hl = (_Float16)(v[j] - (float)hh);
      d[j] = (unsigned int)f2b(hh) | ((unsigned int)f2b(hl) << 16);
    }
    return;
  }
  u -= NH2;
  if (u >= 0 && u < 2048) {
    bias[u] = b_ih[u] + b_hh[u];
    return;
  }
  u -= 2048;
  if (u >= 0 && u < FLAG_INTS) flags[u] = 0;
}

template <bool XPRE>
__global__ void __launch_bounds__(512, 1) recur_kernel(
    const float* __restrict__ x, const float* __restrict__ b_lin,
    const _Float16* __restrict__ xs, const _Float16* __restrict__ wf,
    const _Float16* __restrict__ wlf_hi, const _Float16* __restrict__ wlf_lo,
    unsigned int* __restrict__ hs2, const float* __restrict__ bias, float* __restrict__ out,
    int* __restrict__ flags) {
  const int bid = blockIdx.x;
  const int x8 = bid & 7;                     // XCD under round-robin dispatch
  const int g = x8 >> 1;                      // group on XCD pair {2g,2g+1}
  const int cb = (x8 & 1) * 32 + (bid >> 3);  // 8-d column slice
  const int tid = threadIdx.x;
  const int l = tid & 63, w = tid >> 6;
  const int l15 = l & 15, q = l >> 4;
  const int kh = w & 1, rtp = w >> 1;  // 2 K-halves x 4 row-tiles

  __shared__ _Float16 wlin_h[4 * 16 * 64 * 8];  // 64KB W_lin B-frag hi
  __shared__ _Float16 wlin_l[4 * 16 * 64 * 8];  // 64KB W_lin B-frag lo
  __shared__ float scratch[4608];               // 18KB union: y-merge | ytr | pacc
  __shared__ int s_ab;

  {  // one-time LDS staging of W_lin frags: 4096 float4 units per array (R8 bug: was 2048)
#pragma unroll
    for (int i = 0; i < 8; ++i) {
      int u = tid + i * 512;
      *(float4*)(wlin_h + (size_t)u * 8) = *(const float4*)(wlf_hi + (size_t)u * 8);
      *(float4*)(wlin_l + (size_t)u * 8) = *(const float4*)(wlf_lo + (size_t)u * 8);
    }
    if (tid == 0) s_ab = 0;
  }
  __syncthreads();

  const int dd = l15 & 3, rr = l15 >> 2;
  float bg[2][4];
#pragma unroll
  for (int c2 = 0; c2 < 2; ++c2)
#pragma unroll
    for (int gi = 0; gi < 4; ++gi) bg[c2][gi] = bias[gi * 512 + cb * 8 + c2 * 4 + dd];
  const float blv0 = b_lin[l15], blv1 = b_lin[16 + l15];
  const float blv2 = b_lin[32 + l15], blv3 = b_lin[48 + l15];

  const int Rw = g * 64 + rtp * 16;
  const int rowA = Rw + l15;
  const _Float16* xsA = xs + (size_t)rowA * 524288 + q * 16;
  const float* xfA = x + (size_t)rowA * 262144 + 4 * q;
  const unsigned int* hldA = hs2 + (size_t)rowA * 512 + 4 * q;  // + buf*HS2_U32 + chunk*32
  const int rowE = Rw + 4 * q + rr;

  // gates B-frag base (GLOBAL, L2-resident): ct = 2cb (+1)
  const _Float16* wfb = wf + ((size_t)(2 * cb) * 34) * 1024 + (size_t)l * 16;

  int* abortf = flags + 256 * 64;

  auto ARRIVE = [&](int v) {
    __syncthreads();  // drains this block's LLC atomic stores before the flag
    if (tid == 0) __hip_atomic_store(flags + (size_t)(g * 64 + cb) * 64, v, RLX, AGT);
  };
  auto WAIT = [&](int v) -> bool {
    if (tid < 64) {
      int a = 0;
      int* f = flags + ((size_t)g * 64 + tid) * 64;
      int it = 0;
      while (__hip_atomic_load(f, RLX, AGT) < v) {
        __builtin_amdgcn_s_sleep(1);
        if (++it > 400000) {
          a = 1;
          break;
        }
        if ((it & 255) == 0 && __hip_atomic_load(abortf, RLX, AGT) != 0) {
          a = 1;
          break;
        }
      }
      a = __any(a) ? 1 : 0;
      if (tid == 0) {
        if (a) __hip_atomic_store(abortf, 1, RLX, AGT);
        s_ab = a;
      }
    }
    __syncthreads();
    return s_ab != 0;
  };

  // gates k-chunk, 3-pass hi/lo, B from GLOBAL (L2)
  auto GK3 = [&](const f16x8& ah, const f16x8& al, int KI, f32x4& A0, f32x4& A1) {
    const _Float16* p0 = wfb + (size_t)KI * 1024;
    const _Float16* p1 = p0 + 34 * 1024;
    f16x8 b0h = *(const f16x8*)p0, b0l = *(const f16x8*)(p0 + 8);
    f16x8 b1h = *(const f16x8*)p1, b1l = *(const f16x8*)(p1 + 8);
    A0 = MFMA16(ah, b0h, A0);
    A1 = MFMA16(ah, b1h, A1);
    A0 = MFMA16(al, b0h, A0);
    A1 = MFMA16(al, b1h, A1);
    A0 = MFMA16(ah, b0l, A0);
    A1 = MFMA16(ah, b1l, A1);
  };
  auto XGEMM = [&](int t, f32x4& A0, f32x4& A1) {
    if (XPRE) {
      const _Float16* xA = xsA + (size_t)t * 1024;
#pragma unroll
      for (int i = 0; i < 8; ++i) {
        int kx = kh * 8 + i;
        f16x8 ah = *(const f16x8*)(xA + kx * 64);
        f16x8 al = *(const f16x8*)(xA + kx * 64 + 8);
        GK3(ah, al, kx, A0, A1);
      }
    } else {
      const float* xp = xfA + (size_t)t * 512;
#pragma unroll 2
      for (int i = 0; i < 8; ++i) {
        int kx = kh * 8 + i;
        float4 av = *(const float4*)(xp + kx * 32);
        float4 bv = *(const float4*)(xp + kx * 32 + 16);
        f16x8 ah, al;
        cvt8(av, bv, ah, al);
        GK3(ah, al, kx, A0, A1);
      }
    }
  };

  const f32x4 Z = {0.f, 0.f, 0.f, 0.f};
  float cst[2] = {0.f, 0.f};  // cell state, register-resident for all 512 steps
  f32x4 aC0 = Z, aC1 = Z;
  XGEMM(0, aC0, aC1);  // x-part of step 0

#pragma unroll 1
  for (int s = 0; s < 512; ++s) {
    if (s > 0) {
      if (WAIT(s)) return;  // h_{s-1} published by all 64 peer blocks
    }

    // ---- h fragment loads (hi/lo u32, u64 LLC atomics) ----
    f16x8 hh[8], hl[8];
    const unsigned int* hp0 = hldA + (size_t)(s & 1) * HS2_U32;
#pragma unroll
    for (int i = 0; i < 8; ++i) {
      const unsigned int* hp = hp0 + (kh * 8 + i) * 32;
      u64 u0 = __hip_atomic_load((const u64*)hp, RLX, AGT);
      u64 u1 = __hip_atomic_load((const u64*)(hp + 2), RLX, AGT);
      u64 u2 = __hip_atomic_load((const u64*)(hp + 16), RLX, AGT);
      u64 u3 = __hip_atomic_load((const u64*)(hp + 18), RLX, AGT);
      unsigned int wd[8] = {(unsigned int)u0, (unsigned int)(u0 >> 32),
                            (unsigned int)u1, (unsigned int)(u1 >> 32),
                            (unsigned int)u2, (unsigned int)(u2 >> 32),
                            (unsigned int)u3, (unsigned int)(u3 >> 32)};
#pragma unroll
      for (int j = 0; j < 8; ++j) {
        hh[i][j] = b2f((unsigned short)(wd[j] & 0xffffu));
        hl[i][j] = b2f((unsigned short)(wd[j] >> 16));
      }
    }

    // ---- y-GEMM (logits, K-half partial, 3-pass hi/lo, B from LDS) ----
    f32x4 y0 = Z, y1 = Z, y2 = Z, y3 = Z;
    if (s > 0) {
#pragma unroll
      for (int i = 0; i < 8; ++i) {
        int ki = kh * 8 + i;
        const _Float16* ph0 = wlin_h + ((size_t)(0 * 16 + ki) * 64 + l) * 8;
        const _Float16* ph1 = wlin_h + ((size_t)(1 * 16 + ki) * 64 + l) * 8;
        const _Float16* ph2 = wlin_h + ((size_t)(2 * 16 + ki) * 64 + l) * 8;
        const _Float16* ph3 = wlin_h + ((size_t)(3 * 16 + ki) * 64 + l) * 8;
        f16x8 b0 = *(const f16x8*)ph0, b1 = *(const f16x8*)ph1;
        f16x8 b2 = *(const f16x8*)ph2, b3 = *(const f16x8*)ph3;
        y0 = MFMA16(hh[i], b0, y0);
        y1 = MFMA16(hh[i], b1, y1);
        y2 = MFMA16(hh[i], b2, y2);
        y3 = MFMA16(hh[i], b3, y3);
        y0 = MFMA16(hl[i], b0, y0);
        y1 = MFMA16(hl[i], b1, y1);
        y2 = MFMA16(hl[i], b2, y2);
        y3 = MFMA16(hl[i], b3, y3);
        const _Float16* pl0 = wlin_l + ((size_t)(0 * 16 + ki) * 64 + l) * 8;
        const _Float16* pl1 = wlin_l + ((size_t)(1 * 16 + ki) * 64 + l) * 8;
        const _Float16* pl2 = wlin_l + ((size_t)(2 * 16 + ki) * 64 + l) * 8;
        const _Float16* pl3 = wlin_l + ((size_t)(3 * 16 + ki) * 64 + l) * 8;
        f16x8 c0 = *(const f16x8*)pl0, c1 = *(const f16x8*)pl1;
        f16x8 c2v = *(const f16x8*)pl2, c3 = *(const f16x8*)pl3;
        y0 = MFMA16(hh[i], c0, y0);
        y1 = MFMA16(hh[i], c1, y1);
        y2 = MFMA16(hh[i], c2v, y2);
        y3 = MFMA16(hh[i], c3, y3);
      }
    }
    // ---- h-GEMM ----
#pragma unroll
    for (int i = 0; i < 8; ++i) GK3(hh[i], hl[i], 16 + kh * 8 + i, aC0, aC1);

    if (s > 0) {
      // ---- K-half merge of logits ----
      if (kh == 1) {
#pragma unroll
        for (int r = 0; r < 4; ++r) {
          scratch[((rtp * 4 + 0) * 4 + r) * 64 + l] = y0[r];
          scratch[((rtp * 4 + 1) * 4 + r) * 64 + l] = y1[r];
          scratch[((rtp * 4 + 2) * 4 + r) * 64 + l] = y2[r];
          scratch[((rtp * 4 + 3) * 4 + r) * 64 + l] = y3[r];
        }
      }
      __syncthreads();  // S1
      float la0[4], la1[4], la2[4], la3[4];
      if (kh == 0) {
#pragma unroll
        for (int r = 0; r < 4; ++r) {
          la0[r] = y0[r] + scratch[((rtp * 4 + 0) * 4 + r) * 64 + l] + blv0;
          la1[r] = y1[r] + scratch[((rtp * 4 + 1) * 4 + r) * 64 + l] + blv1;
          la2[r] = y2[r] + scratch[((rtp * 4 + 2) * 4 + r) * 64 + l] + blv2;
          la3[r] = y3[r] + scratch[((rtp * 4 + 3) * 4 + r) * 64 + l] + blv3;
        }
        // in-block softmax per row (reduce over 16 lanes x 4 ct)
#pragma unroll
        for (int r = 0; r < 4; ++r) {
          float mx = fmaxf(fmaxf(la0[r], la1[r]), fmaxf(la2[r], la3[r]));
          mx = fmaxf(mx, __shfl_xor(mx, 1));
          mx = fmaxf(mx, __shfl_xor(mx, 2));
          mx = fmaxf(mx, __shfl_xor(mx, 4));
          mx = fmaxf(mx, __shfl_xor(mx, 8));
          float e0 = __expf(la0[r] - mx), e1 = __expf(la1[r] - mx);
          float e2 = __expf(la2[r] - mx), e3 = __expf(la3[r] - mx);
          float sm = e0 + e1 + e2 + e3;
          sm += __shfl_xor(sm, 1);
          sm += __shfl_xor(sm, 2);
          sm += __shfl_xor(sm, 4);
          sm += __shfl_xor(sm, 8);
          float inv = 1.f / sm;
          la0[r] = e0 * inv;
          la1[r] = e1 * inv;
          la2[r] = e2 * inv;
          la3[r] = e3 * inv;
        }
        if (cb == 0) {
#pragma unroll
          for (int r = 0; r < 4; ++r) {
            size_t ob = ((size_t)(g * 64 + rtp * 16 + 4 * q + r) * 512 + (s - 1)) * 64 + l15;
            out[ob] = la0[r];
            out[ob + 16] = la1[r];
            out[ob + 32] = la2[r];
            out[ob + 48] = la3[r];
          }
        }
      }
      __syncthreads();  // S2: merge reads done; scratch re-used as ytr (hi|lo planes)
      if (kh == 0) {
        _Float16* yt = (_Float16*)scratch;
#pragma unroll
        for (int r = 0; r < 4; ++r) {
          int row = rtp * 16 + 4 * q + r;
          float v[4] = {la0[r], la1[r], la2[r], la3[r]};
#pragma unroll
          for (int ct = 0; ct < 4; ++ct) {
            _Float16 vh = (_Float16)v[ct];
            _Float16 vl = (_Float16)(v[ct] - (float)vh);
            yt[row * 136 + ct * 16 + l15] = vh;
            yt[row * 136 + 72 + ct * 16 + l15] = vl;
          }
        }
      }
      __syncthreads();  // S3: ytr ready
      {
        const _Float16* yt = (const _Float16*)scratch + (rtp * 16 + l15) * 136 + kh * 32 + 4 * q;
        union {
          u64 d[2];
          f16x8 v;
        } th, tl;
        th.d[0] = *(const u64*)yt;
        th.d[1] = *(const u64*)(yt + 16);
        tl.d[0] = *(const u64*)(yt + 72);
        tl.d[1] = *(const u64*)(yt + 88);
        GK3(th.v, tl.v, 32 + kh, aC0, aC1);  // y-feedback k-chunk (hi/lo)
      }
      __syncthreads();  // S4: ytr reads done before scratch re-used as pacc
    }

    // ---- K-half merge of gate pre-activations ----
    if (kh == 1) {
#pragma unroll
      for (int r = 0; r < 4; ++r) {
        scratch[((rtp * 2 + 0) * 4 + r) * 64 + l] = aC0[r];
        scratch[((rtp * 2 + 1) * 4 + r) * 64 + l] = aC1[r];
      }
    }
    __syncthreads();  // S5
    if (kh == 0) {
#pragma unroll
      for (int r = 0; r < 4; ++r) {
        aC0[r] += scratch[((rtp * 2 + 0) * 4 + r) * 64 + l];
        aC1[r] += scratch[((rtp * 2 + 1) * 4 + r) * 64 + l];
      }
      // ---- elementwise LSTM + hi/lo u32 h store ----
#pragma unroll
      for (int c2 = 0; c2 < 2; ++c2) {
        f32x4 A = c2 ? aC1 : aC0;
        float z[4];
#pragma unroll
        for (int gi = 0; gi < 4; ++gi) {
          int src = (l & 48) | (gi * 4 + dd);
          float v0 = __shfl(A[0], src), v1 = __shfl(A[1], src);
          float v2 = __shfl(A[2], src), v3 = __shfl(A[3], src);
          z[gi] = (rr == 0) ? v0 : (rr == 1) ? v1 : (rr == 2) ? v2 : v3;
        }
        float zi = z[0] + bg[c2][0], zf = z[1] + bg[c2][1];
        float zg = z[2] + bg[c2][2], zo = z[3] + bg[c2][3];
        float iv = 1.f / (1.f + __expf(-zi));
        float fv = 1.f / (1.f + __expf(-zf));
        float eg = __expf(2.f * zg);
        float gv = 1.f - 2.f / (eg + 1.f);
        float ov = 1.f / (1.f + __expf(-zo));
        float cn = fv * cst[c2] + iv * gv;
        cst[c2] = cn;
        float ec = __expf(2.f * cn);
        float th2 = 1.f - 2.f / (ec + 1.f);
        float hv = ov * th2;
        _Float16 hhv = (_Float16)hv;
        _Float16 hlv = (_Float16)(hv - (float)hhv);
        unsigned int pk = (unsigned int)f2b(hhv) | ((unsigned int)f2b(hlv) << 16);
        int dglob = cb * 8 + c2 * 4 + dd;
        __hip_atomic_store(hs2 + (size_t)((s + 1) & 1) * HS2_U32 + rowE * 512 + dglob, pk, RLX,
                           AGT);
      }
    }
    ARRIVE(s + 1);  // drain + publish h_s
    if (s < 511) {  // x-GEMM for s+1 runs in the barrier's propagation shadow
      f32x4 aN0 = Z, aN1 = Z;
      XGEMM(s + 1, aN0, aN1);
      aC0 = aN0;
      aC1 = aN1;
    }
  }

  // ---- epilogue: y_511 from h_511 (buffer 0), cb==0 blocks only ----
  if (cb != 0) return;
  if (WAIT(512)) return;
  {
    f16x8 hh[8], hl[8];
    const unsigned int* hp0 = hldA;  // buffer (512&1)==0
#pragma unroll
    for (int i = 0; i < 8; ++i) {
      const unsigned int* hp = hp0 + (kh * 8 + i) * 32;
      u64 u0 = __hip_atomic_load((const u64*)hp, RLX, AGT);
      u64 u1 = __hip_atomic_load((const u64*)(hp + 2), RLX, AGT);
      u64 u2 = __hip_atomic_load((const u64*)(hp + 16), RLX, AGT);
      u64 u3 = __hip_atomic_load((const u64*)(hp + 18), RLX, AGT);
      unsigned int wd[8] = {(unsigned int)u0, (unsigned int)(u0 >> 32),
                            (unsigned int)u1, (unsigned int)(u1 >> 32),
                            (unsigned int)u2, (unsigned int)(u2 >> 32),
                            (unsigned int)u3, (unsigned int)(u3 >> 32)};
#pragma unroll
      for (int j = 0; j < 8; ++j) {
        hh[i][j] = b2f((unsigned short)(wd[j] & 0xffffu));
        hl[i][j] = b2f((unsigned short)(wd[j] >> 16));
      }
    }
    f32x4 y0 = Z, y1 = Z, y2 = Z, y3 = Z;
#pragma unroll
    for (int i = 0; i < 8; ++i) {
      int ki = kh * 8 + i;
      const _Float16* ph0 = wlin_h + ((size_t)(0 * 16 + ki) * 64 + l) * 8;
      const _Float16* ph1 = wlin_h + ((size_t)(1 * 16 + ki) * 64 + l) * 8;
      const _Float16* ph2 = wlin_h + ((size_t)(2 * 16 + ki) * 64 + l) * 8;
      const _Float16* ph3 = wlin_h + ((size_t)(3 * 16 + ki) * 64 + l) * 8;
      f16x8 b0 = *(const f16x8*)ph0, b1 = *(const f16x8*)ph1;
      f16x8 b2 = *(const f16x8*)ph2, b3 = *(const f16x8*)ph3;
      y0 = MFMA16(hh[i], b0, y0);
      y1 = MFMA16(hh[i], b1, y1);
      y2 = MFMA16(hh[i], b2, y2);
      y3 = MFMA16(hh[i], b3, y3);
      y0 = MFMA16(hl[i], b0, y0);
      y1 = MFMA16(hl[i], b1, y1);
      y2 = MFMA16(hl[i], b2, y2);
      y3 = MFMA16(hl[i], b3, y3);
      const _Float16* pl0 = wlin_l + ((size_t)(0 * 16 + ki) * 64 + l) * 8;
      const _Float16* pl1 = wlin_l + ((size_t)(1 * 16 + ki) * 64 + l) * 8;
      const _Float16* pl2 = wlin_l + ((size_t)(2 * 16 + ki) * 64 + l) * 8;
      const _Float16* pl3 = wlin_l + ((size_t)(3 * 16 + ki) * 64 + l) * 8;
      f16x8 c0 = *(const f16x8*)pl0, c1 = *(const f16x8*)pl1;
      f16x8 c2v = *(const f16x8*)pl2, c3 = *(const f16x8*)pl3;
      y0 = MFMA16(hh[i], c0, y0);
      y1 = MFMA16(hh[i], c1, y1);
      y2 = MFMA16(hh[i], c2v, y2);
      y3 = MFMA16(hh[i], c3, y3);
    }
    if (kh == 1) {
#pragma unroll
      for (int r = 0; r < 4; ++r) {
        scratch[((rtp * 4 + 0) * 4 + r) * 64 + l] = y0[r];
        scratch[((rtp * 4 + 1) * 4 + r) * 64 + l] = y1[r];
        scratch[((rtp * 4 + 2) * 4 + r) * 64 + l] = y2[r];
        scratch[((rtp * 4 + 3) * 4 + r) * 64 + l] = y3[r];
      }
    }
    __syncthreads();
    if (kh == 0) {
      float la0[4], la1[4], la2[4], la3[4];
#pragma unroll
      for (int r = 0; r < 4; ++r) {
        la0[r] = y0[r] + scratch[((rtp * 4 + 0) * 4 + r) * 64 + l] + blv0;
        la1[r] = y1[r] + scratch[((rtp * 4 + 1) * 4 + r) * 64 + l] + blv1;
        la2[r] = y2[r] + scratch[((rtp * 4 + 2) * 4 + r) * 64 + l] + blv2;
        la3[r] = y3[r] + scratch[((rtp * 4 + 3) * 4 + r) * 64 + l] + blv3;
      }
#pragma unroll
      for (int r = 0; r < 4; ++r) {
        float mx = fmaxf(fmaxf(la0[r], la1[r]), fmaxf(la2[r], la3[r]));
        mx = fmaxf(mx, __shfl_xor(mx, 1));
        mx = fmaxf(mx, __shfl_xor(mx, 2));
        mx = fmaxf(mx, __shfl_xor(mx, 4));
        mx = fmaxf(mx, __shfl_xor(mx, 8));
        float e0 = __expf(la0[r] - mx), e1 = __expf(la1[r] - mx);
        float e2 = __expf(la2[r] - mx), e3 = __expf(la3[r] - mx);
        float sm = e0 + e1 + e2 + e3;
        sm += __shfl_xor(sm, 1);
        sm += __shfl_xor(sm, 2);
        sm += __shfl_xor(sm, 4);
        sm += __shfl_xor(sm, 8);
        float inv = 1.f / sm;
        size_t ob = ((size_t)(g * 64 + rtp * 16 + 4 * q + r) * 512 + 511) * 64 + l15;
        out[ob] = e0 * inv;
        out[ob + 16] = e1 * inv;
        out[ob + 32] = e2 * inv;
        out[ob + 48] = e3 * inv;
      }
    }
  }
}

extern "C" void kernel_launch(void* const* d_in, const int* in_sizes, int n_in, void* d_out,
                              int out_size, void* d_ws, size_t ws_size, hipStream_t stream) {
  const float* x = (const float*)d_in[0];
  const float* init_h = (const float*)d_in[1];
  const float* W_ih = (const float*)d_in[2];
  const float* b_ih = (const float*)d_in[3];
  const float* W_hh = (const float*)d_in[4];
  const float* b_hh = (const float*)d_in[5];
  const float* W_lin = (const float*)d_in[6];
  const float* b_lin = (const float*)d_in[7];
  float* out = (float*)d_out;
  (void)in_sizes;
  (void)n_in;
  (void)out_size;

  char* ws = (char*)d_ws;
  size_t off = 0;
  auto take = [&](size_t bytes) -> char* {
    char* r = ws + off;
    off = (off + bytes + 255) & ~(size_t)255;
    return r;
  };
  const size_t WF_E = (size_t)128 * 34 * 64 * 16;   // gates weight f16 elems
  const size_t WLF_E = (size_t)4 * 16 * 64 * 8;     // W_lin frag f16 elems (x2 hi/lo)
  const size_t XS_E = (size_t)256 * 512 * 16 * 64;  // pre-split x f16 elems

  _Float16* wf = (_Float16*)take(WF_E * 2);
  _Float16* wlf_hi = (_Float16*)take(WLF_E * 2);
  _Float16* wlf_lo = (_Float16*)take(WLF_E * 2);
  unsigned int* hs2 = (unsigned int*)take((size_t)2 * HS2_U32 * 4);
  float* bias = (float*)take(2048 * 4);
  int* flags = (int*)take((size_t)FLAG_INTS * 4);
  if (ws_size < off) return;  // cannot run -> visible failure
  _Float16* xs = (_Float16*)(ws + off);
  const bool xpre = (ws_size >= off + XS_E * 2);

  if (xpre) {
    const long total = 8388608L + 278528 + 4096 + 32768 + 2048 + FLAG_INTS;
    prep_kernel<true><<<(int)((total + 255) / 256), 256, 0, stream>>>(
        x, init_h, W_ih, b_ih, W_hh, b_hh, W_lin, xs, wf, wlf_hi, wlf_lo, hs2, bias, flags);
    recur_kernel<true><<<256, 512, 0, stream>>>(x, b_lin, xs, wf, wlf_hi, wlf_lo, hs2, bias, out,
                                                flags);
  } else {
    const long total = 278528L + 4096 + 32768 + 2048 + FLAG_INTS;
    prep_kernel<false><<<(int)((total + 255) / 256), 256, 0, stream>>>(
        x, init_h, W_ih, b_ih, W_hh, b_hh, W_lin, xs, wf, wlf_hi, wlf_lo, hs2, bias, flags);
    recur_kernel<false><<<256, 512, 0, stream>>>(x, b_lin, xs, wf, wlf_hi, wlf_lo, hs2, bias, out,
                                                 flags);
  }
}

// Round 10
// 9622.971 us; speedup vs baseline: 1.4317x; 1.4317x over previous
//
#include <hip/hip_runtime.h>
#include <cstdint>
#include <cstddef>

// Autoregressive LSTM cell with softmax feedback. B=256, T=512, D=512, N=64.
// R10 = R9's single-barrier structure with the L2-thrash fixed.
// R9 lesson (FETCH 15.3GB): 32 blocks/XCD x 136KB gates slice = 4.35MB > 4MB L2 ->
// per-step re-stream from memory. Fix: gates HI plane -> LDS (68KB, like R6),
// gates LO plane -> global/L2 (32 x 68KB = 2.18MB/XCD, fits); W_lin HI only -> LDS
// (64KB; dropping the h*Wlin_lo pass adds ~1e-4 to y, budget-checked).
// Also: output write distributed across blocks (each block writes its own y-column,
// 256B/step) instead of one block per group writing 16KB -> removes barrier straggler.
// Numerics: full hi/lo on every recurrence-path operand (R7 lesson). h = hi/lo
// u32/elem, LLC relaxed atomics. Single flag barrier per step, timeout->abort.

typedef _Float16 f16x8 __attribute__((ext_vector_type(8)));
typedef float f32x4 __attribute__((ext_vector_type(4)));
typedef unsigned long long u64;

#define MFMA16(a, b, c_) __builtin_amdgcn_mfma_f32_16x16x32_f16((a), (b), (c_), 0, 0, 0)
#define AGT __HIP_MEMORY_SCOPE_AGENT
#define RLX __ATOMIC_RELAXED

#define FLAG_INTS (256 * 64 + 64)  // 256 padded flag slots + abort word
#define HS2_U32 131072             // per h buffer: 256 rows * 512 u32 (hi|lo<<16)

static __device__ __forceinline__ unsigned short f2b(_Float16 h) {
  return __builtin_bit_cast(unsigned short, h);
}
static __device__ __forceinline__ _Float16 b2f(unsigned short s) {
  return __builtin_bit_cast(_Float16, s);
}

__device__ __forceinline__ void cvt8(const float4 a, const float4 b, f16x8& hi, f16x8& lo) {
  float v[8] = {a.x, a.y, a.z, a.w, b.x, b.y, b.z, b.w};
#pragma unroll
  for (int j = 0; j < 8; ++j) {
    _Float16 h = (_Float16)v[j];
    hi[j] = h;
    lo[j] = (_Float16)(v[j] - (float)h);
  }
}

// ---------------------------------------------------------------------------
// prep. Slot map sigma(q,j)=4q+(j&3)+16*(j>>2) on A and B frags (R2-R9 verified).
// wf_hi/wf_lo (gates B-frags, SEPARATE planes): [(ct*34+ki)*64+l]*8,
//   ct=cb*2+cth, col(l15)=(l15>>2)*512+cb*8+cth*4+(l15&3).
// wlf_hi (y-GEMM B-frags, hi only): [(ct*16+ki)*64+l]*8, col=ct*16+(l&15).
// hs2: u32 row-major [2][256][512], value = f16hi | f16lo<<16; buffer0 = init_h.
// ---------------------------------------------------------------------------
template <bool XPRE>
__global__ void prep_kernel(const float* __restrict__ x, const float* __restrict__ init_h,
                            const float* __restrict__ W_ih, const float* __restrict__ b_ih,
                            const float* __restrict__ W_hh, const float* __restrict__ b_hh,
                            const float* __restrict__ W_lin, _Float16* __restrict__ xs,
                            _Float16* __restrict__ wf_hi, _Float16* __restrict__ wf_lo,
                            _Float16* __restrict__ wlf_hi, unsigned int* __restrict__ hs2,
                            float* __restrict__ bias, int* __restrict__ flags) {
  const long NX = XPRE ? 256L * 512 * 16 * 4 : 0;
  const int NWF = 128 * 34 * 64;
  const int NWLF = 4 * 16 * 64;
  const int NH2 = 256 * 128;
  long tid = (long)blockIdx.x * 256 + threadIdx.x;

  if (XPRE && tid < NX) {
    int q = tid & 3, ki = (tid >> 2) & 15, t = (tid >> 6) & 511;
    int row = (int)(tid >> 15);
    const float* s = x + (((size_t)row * 512 + t) * 512 + ki * 32 + 4 * q);
    float4 a = *(const float4*)s, b = *(const float4*)(s + 16);
    f16x8 hi, lo;
    cvt8(a, b, hi, lo);
    _Float16* d = xs + ((((size_t)row * 512 + t) * 16 + ki) * 64 + q * 16);
    *(f16x8*)d = hi;
    *(f16x8*)(d + 8) = lo;
    return;
  }
  long u = tid - NX;
  if (u >= 0 && u < NWF) {
    int l = (int)(u & 63);
    int u2 = (int)(u >> 6);
    int ki = u2 % 34, ct = u2 / 34;
    int cb = ct >> 1, cth = ct & 1;
    int l15 = l & 15;
    int col = (l15 >> 2) * 512 + cb * 8 + cth * 4 + (l15 & 3);
    int k = ki * 32 + 4 * (l >> 4);
    float4 a, b;
    if (k < 512) {
      const float* p = W_ih + (size_t)col * 576;
      a = *(const float4*)(p + k);
      b = *(const float4*)(p + k + 16);
    } else if (k < 1024) {
      const float* p = W_hh + (size_t)col * 512;
      a = *(const float4*)(p + k - 512);
      b = *(const float4*)(p + k - 512 + 16);
    } else {
      const float* p = W_ih + (size_t)col * 576 + 512;
      a = *(const float4*)(p + k - 1024);
      b = *(const float4*)(p + k - 1024 + 16);
    }
    f16x8 hi, lo;
    cvt8(a, b, hi, lo);
    size_t idx = (((size_t)ct * 34 + ki) * 64 + l) * 8;
    *(f16x8*)(wf_hi + idx) = hi;
    *(f16x8*)(wf_lo + idx) = lo;
    return;
  }
  u -= NWF;
  if (u >= 0 && u < NWLF) {
    int l = (int)(u & 63);
    int u2 = (int)(u >> 6);
    int ki = u2 & 15, ct = u2 >> 4;
    int col = ct * 16 + (l & 15);
    int k = ki * 32 + 4 * (l >> 4);
    const float* p = W_lin + (size_t)col * 512;
    float4 a = *(const float4*)(p + k), b = *(const float4*)(p + k + 16);
    f16x8 hi, lo;
    cvt8(a, b, hi, lo);
    _Float16* dh = wlf_hi + ((size_t)(ct * 16 + ki) * 64 + l) * 8;
    *(f16x8*)dh = hi;
    return;
  }
  u -= NWLF;
  if (u >= 0 && u < NH2) {
    int g4 = (int)(u & 127), row = (int)(u >> 7);
    const float* s = init_h + (size_t)row * 512 + g4 * 4;
    float4 a = *(const float4*)s;
    float v[4] = {a.x, a.y, a.z, a.w};
    unsigned int* d = hs2 + (size_t)row * 512 + g4 * 4;  // buffer 0
#pragma unroll
    for (int j = 0; j < 4; ++j) {
      _Float16 hh = (_Float16)v[j];
      _Float16 hl = (_Float16)(v[j] - (float)hh);
      d[j] = (unsigned int)f2b(hh) | ((unsigned int)f2b(hl) << 16);
    }
    return;
  }
  u -= NH2;
  if (u >= 0 && u < 2048) {
    bias[u] = b_ih[u] + b_hh[u];
    return;
  }
  u -= 2048;
  if (u >= 0 && u < FLAG_INTS) flags[u] = 0;
}

template <bool XPRE>
__global__ void __launch_bounds__(512, 1) recur_kernel(
    const float* __restrict__ x, const float* __restrict__ b_lin,
    const _Float16* __restrict__ xs, const _Float16* __restrict__ wf_hi,
    const _Float16* __restrict__ wf_lo, const _Float16* __restrict__ wlf_hi,
    unsigned int* __restrict__ hs2, const float* __restrict__ bias, float* __restrict__ out,
    int* __restrict__ flags) {
  const int bid = blockIdx.x;
  const int x8 = bid & 7;                     // XCD under round-robin dispatch
  const int g = x8 >> 1;                      // group on XCD pair {2g,2g+1}
  const int cb = (x8 & 1) * 32 + (bid >> 3);  // 8-d column slice
  const int tid = threadIdx.x;
  const int l = tid & 63, w = tid >> 6;
  const int l15 = l & 15, q = l >> 4;
  const int kh = w & 1, rtp = w >> 1;  // 2 K-halves x 4 row-tiles

  __shared__ _Float16 wfl_hi[2 * 34 * 64 * 8];  // 68KB gates B-frag hi (LDS)
  __shared__ _Float16 wlin_h[4 * 16 * 64 * 8];  // 64KB W_lin B-frag hi (LDS)
  __shared__ float scratch[4608];               // 18KB union: y-merge | ytr | pacc
  __shared__ int s_ab;

  {  // one-time LDS staging
    const _Float16* srcw = wf_hi + (size_t)(2 * cb) * 17408;
#pragma unroll
    for (int i = 0; i < 9; ++i) {
      int u = tid + i * 512;
      if (u < 4352) *(float4*)(wfl_hi + (size_t)u * 8) = *(const float4*)(srcw + (size_t)u * 8);
    }
#pragma unroll
    for (int i = 0; i < 8; ++i) {
      int u = tid + i * 512;
      *(float4*)(wlin_h + (size_t)u * 8) = *(const float4*)(wlf_hi + (size_t)u * 8);
    }
    if (tid == 0) s_ab = 0;
  }
  __syncthreads();

  const int dd = l15 & 3, rr = l15 >> 2;
  float bg[2][4];
#pragma unroll
  for (int c2 = 0; c2 < 2; ++c2)
#pragma unroll
    for (int gi = 0; gi < 4; ++gi) bg[c2][gi] = bias[gi * 512 + cb * 8 + c2 * 4 + dd];
  const float blv0 = b_lin[l15], blv1 = b_lin[16 + l15];
  const float blv2 = b_lin[32 + l15], blv3 = b_lin[48 + l15];

  const int Rw = g * 64 + rtp * 16;
  const int rowA = Rw + l15;
  const _Float16* xsA = xs + (size_t)rowA * 524288 + q * 16;
  const float* xfA = x + (size_t)rowA * 262144 + 4 * q;
  const unsigned int* hldA = hs2 + (size_t)rowA * 512 + 4 * q;
  const int rowE = Rw + 4 * q + rr;

  // gates LO B-frag base (GLOBAL, L2-resident: 32 blocks/XCD x 68KB = 2.18MB < 4MB)
  const _Float16* wflo_b = wf_lo + (size_t)(2 * cb) * 17408 + (size_t)l * 8;

  int* abortf = flags + 256 * 64;

  auto ARRIVE = [&](int v) {
    __syncthreads();  // drains this block's LLC atomic stores before the flag
    if (tid == 0) __hip_atomic_store(flags + (size_t)(g * 64 + cb) * 64, v, RLX, AGT);
  };
  auto WAIT = [&](int v) -> bool {
    if (tid < 64) {
      int a = 0;
      int* f = flags + ((size_t)g * 64 + tid) * 64;
      int it = 0;
      while (__hip_atomic_load(f, RLX, AGT) < v) {
        __builtin_amdgcn_s_sleep(1);
        if (++it > 400000) {
          a = 1;
          break;
        }
        if ((it & 255) == 0 && __hip_atomic_load(abortf, RLX, AGT) != 0) {
          a = 1;
          break;
        }
      }
      a = __any(a) ? 1 : 0;
      if (tid == 0) {
        if (a) __hip_atomic_store(abortf, 1, RLX, AGT);
        s_ab = a;
      }
    }
    __syncthreads();
    return s_ab != 0;
  };

  // gates k-chunk, 3-pass hi/lo: B-hi from LDS, B-lo from GLOBAL (L2)
  auto GK3 = [&](const f16x8& ah, const f16x8& al, int KI, f32x4& A0, f32x4& A1) {
    const _Float16* ph0 = wfl_hi + ((size_t)KI * 64 + l) * 8;
    const _Float16* ph1 = ph0 + 17408;
    const _Float16* pl0 = wflo_b + (size_t)KI * 512;
    const _Float16* pl1 = pl0 + 17408;
    f16x8 b0h = *(const f16x8*)ph0, b1h = *(const f16x8*)ph1;
    f16x8 b0l = *(const f16x8*)pl0, b1l = *(const f16x8*)pl1;
    A0 = MFMA16(ah, b0h, A0);
    A1 = MFMA16(ah, b1h, A1);
    A0 = MFMA16(al, b0h, A0);
    A1 = MFMA16(al, b1h, A1);
    A0 = MFMA16(ah, b0l, A0);
    A1 = MFMA16(ah, b1l, A1);
  };
  auto XGEMM = [&](int t, f32x4& A0, f32x4& A1) {
    if (XPRE) {
      const _Float16* xA = xsA + (size_t)t * 1024;
#pragma unroll
      for (int i = 0; i < 8; ++i) {
        int kx = kh * 8 + i;
        f16x8 ah = *(const f16x8*)(xA + kx * 64);
        f16x8 al = *(const f16x8*)(xA + kx * 64 + 8);
        GK3(ah, al, kx, A0, A1);
      }
    } else {
      const float* xp = xfA + (size_t)t * 512;
#pragma unroll 2
      for (int i = 0; i < 8; ++i) {
        int kx = kh * 8 + i;
        float4 av = *(const float4*)(xp + kx * 32);
        float4 bv = *(const float4*)(xp + kx * 32 + 16);
        f16x8 ah, al;
        cvt8(av, bv, ah, al);
        GK3(ah, al, kx, A0, A1);
      }
    }
  };

  const f32x4 Z = {0.f, 0.f, 0.f, 0.f};
  float cst[2] = {0.f, 0.f};  // cell state, register-resident for all 512 steps
  f32x4 aC0 = Z, aC1 = Z;
  XGEMM(0, aC0, aC1);  // x-part of step 0

  const int ctW = cb >> 4, lW = cb & 15;  // this block's output column mapping

#pragma unroll 1
  for (int s = 0; s < 512; ++s) {
    if (s > 0) {
      if (WAIT(s)) return;  // h_{s-1} published by all 64 peer blocks
    }

    // ---- h fragment loads (hi/lo u32, u64 LLC atomics) ----
    f16x8 hh[8], hl[8];
    const unsigned int* hp0 = hldA + (size_t)(s & 1) * HS2_U32;
#pragma unroll
    for (int i = 0; i < 8; ++i) {
      const unsigned int* hp = hp0 + (kh * 8 + i) * 32;
      u64 u0 = __hip_atomic_load((const u64*)hp, RLX, AGT);
      u64 u1 = __hip_atomic_load((const u64*)(hp + 2), RLX, AGT);
      u64 u2 = __hip_atomic_load((const u64*)(hp + 16), RLX, AGT);
      u64 u3 = __hip_atomic_load((const u64*)(hp + 18), RLX, AGT);
      unsigned int wd[8] = {(unsigned int)u0, (unsigned int)(u0 >> 32),
                            (unsigned int)u1, (unsigned int)(u1 >> 32),
                            (unsigned int)u2, (unsigned int)(u2 >> 32),
                            (unsigned int)u3, (unsigned int)(u3 >> 32)};
#pragma unroll
      for (int j = 0; j < 8; ++j) {
        hh[i][j] = b2f((unsigned short)(wd[j] & 0xffffu));
        hl[i][j] = b2f((unsigned short)(wd[j] >> 16));
      }
    }

    // ---- y-GEMM (logits, K-half partial, 2-pass: hh*Wh + hl*Wh, B from LDS) ----
    f32x4 y0 = Z, y1 = Z, y2 = Z, y3 = Z;
    if (s > 0) {
#pragma unroll
      for (int i = 0; i < 8; ++i) {
        int ki = kh * 8 + i;
        const _Float16* ph0 = wlin_h + ((size_t)(0 * 16 + ki) * 64 + l) * 8;
        const _Float16* ph1 = wlin_h + ((size_t)(1 * 16 + ki) * 64 + l) * 8;
        const _Float16* ph2 = wlin_h + ((size_t)(2 * 16 + ki) * 64 + l) * 8;
        const _Float16* ph3 = wlin_h + ((size_t)(3 * 16 + ki) * 64 + l) * 8;
        f16x8 b0 = *(const f16x8*)ph0, b1 = *(const f16x8*)ph1;
        f16x8 b2 = *(const f16x8*)ph2, b3 = *(const f16x8*)ph3;
        y0 = MFMA16(hh[i], b0, y0);
        y1 = MFMA16(hh[i], b1, y1);
        y2 = MFMA16(hh[i], b2, y2);
        y3 = MFMA16(hh[i], b3, y3);
        y0 = MFMA16(hl[i], b0, y0);
        y1 = MFMA16(hl[i], b1, y1);
        y2 = MFMA16(hl[i], b2, y2);
        y3 = MFMA16(hl[i], b3, y3);
      }
    }
    // ---- h-GEMM ----
#pragma unroll
    for (int i = 0; i < 8; ++i) GK3(hh[i], hl[i], 16 + kh * 8 + i, aC0, aC1);

    if (s > 0) {
      // ---- K-half merge of logits ----
      if (kh == 1) {
#pragma unroll
        for (int r = 0; r < 4; ++r) {
          scratch[((rtp * 4 + 0) * 4 + r) * 64 + l] = y0[r];
          scratch[((rtp * 4 + 1) * 4 + r) * 64 + l] = y1[r];
          scratch[((rtp * 4 + 2) * 4 + r) * 64 + l] = y2[r];
          scratch[((rtp * 4 + 3) * 4 + r) * 64 + l] = y3[r];
        }
      }
      __syncthreads();  // S1
      float la0[4], la1[4], la2[4], la3[4];
      if (kh == 0) {
#pragma unroll
        for (int r = 0; r < 4; ++r) {
          la0[r] = y0[r] + scratch[((rtp * 4 + 0) * 4 + r) * 64 + l] + blv0;
          la1[r] = y1[r] + scratch[((rtp * 4 + 1) * 4 + r) * 64 + l] + blv1;
          la2[r] = y2[r] + scratch[((rtp * 4 + 2) * 4 + r) * 64 + l] + blv2;
          la3[r] = y3[r] + scratch[((rtp * 4 + 3) * 4 + r) * 64 + l] + blv3;
        }
        // in-block softmax per row (reduce over 16 lanes x 4 ct)
#pragma unroll
        for (int r = 0; r < 4; ++r) {
          float mx = fmaxf(fmaxf(la0[r], la1[r]), fmaxf(la2[r], la3[r]));
          mx = fmaxf(mx, __shfl_xor(mx, 1));
          mx = fmaxf(mx, __shfl_xor(mx, 2));
          mx = fmaxf(mx, __shfl_xor(mx, 4));
          mx = fmaxf(mx, __shfl_xor(mx, 8));
          float e0 = __expf(la0[r] - mx), e1 = __expf(la1[r] - mx);
          float e2 = __expf(la2[r] - mx), e3 = __expf(la3[r] - mx);
          float sm = e0 + e1 + e2 + e3;
          sm += __shfl_xor(sm, 1);
          sm += __shfl_xor(sm, 2);
          sm += __shfl_xor(sm, 4);
          sm += __shfl_xor(sm, 8);
          float inv = 1.f / sm;
          la0[r] = e0 * inv;
          la1[r] = e1 * inv;
          la2[r] = e2 * inv;
          la3[r] = e3 * inv;
        }
        // distributed output write: this block writes ONLY its column cb (256B/group)
        if (l15 == lW) {
#pragma unroll
          for (int r = 0; r < 4; ++r) {
            float vv = (ctW == 0) ? la0[r] : (ctW == 1) ? la1[r] : (ctW == 2) ? la2[r] : la3[r];
            out[((size_t)(g * 64 + rtp * 16 + 4 * q + r) * 512 + (s - 1)) * 64 + cb] = vv;
          }
        }
      }
      __syncthreads();  // S2: merge reads done; scratch re-used as ytr (hi|lo planes)
      if (kh == 0) {
        _Float16* yt = (_Float16*)scratch;
#pragma unroll
        for (int r = 0; r < 4; ++r) {
          int row = rtp * 16 + 4 * q + r;
          float v[4] = {la0[r], la1[r], la2[r], la3[r]};
#pragma unroll
          for (int ct = 0; ct < 4; ++ct) {
            _Float16 vh = (_Float16)v[ct];
            _Float16 vl = (_Float16)(v[ct] - (float)vh);
            yt[row * 136 + ct * 16 + l15] = vh;
            yt[row * 136 + 72 + ct * 16 + l15] = vl;
          }
        }
      }
      __syncthreads();  // S3: ytr ready
      {
        const _Float16* yt = (const _Float16*)scratch + (rtp * 16 + l15) * 136 + kh * 32 + 4 * q;
        union {
          u64 d[2];
          f16x8 v;
        } th, tl;
        th.d[0] = *(const u64*)yt;
        th.d[1] = *(const u64*)(yt + 16);
        tl.d[0] = *(const u64*)(yt + 72);
        tl.d[1] = *(const u64*)(yt + 88);
        GK3(th.v, tl.v, 32 + kh, aC0, aC1);  // y-feedback k-chunk (hi/lo)
      }
      __syncthreads();  // S4: ytr reads done before scratch re-used as pacc
    }

    // ---- K-half merge of gate pre-activations ----
    if (kh == 1) {
#pragma unroll
      for (int r = 0; r < 4; ++r) {
        scratch[((rtp * 2 + 0) * 4 + r) * 64 + l] = aC0[r];
        scratch[((rtp * 2 + 1) * 4 + r) * 64 + l] = aC1[r];
      }
    }
    __syncthreads();  // S5
    if (kh == 0) {
#pragma unroll
      for (int r = 0; r < 4; ++r) {
        aC0[r] += scratch[((rtp * 2 + 0) * 4 + r) * 64 + l];
        aC1[r] += scratch[((rtp * 2 + 1) * 4 + r) * 64 + l];
      }
      // ---- elementwise LSTM + hi/lo u32 h store ----
#pragma unroll
      for (int c2 = 0; c2 < 2; ++c2) {
        f32x4 A = c2 ? aC1 : aC0;
        float z[4];
#pragma unroll
        for (int gi = 0; gi < 4; ++gi) {
          int src = (l & 48) | (gi * 4 + dd);
          float v0 = __shfl(A[0], src), v1 = __shfl(A[1], src);
          float v2 = __shfl(A[2], src), v3 = __shfl(A[3], src);
          z[gi] = (rr == 0) ? v0 : (rr == 1) ? v1 : (rr == 2) ? v2 : v3;
        }
        float zi = z[0] + bg[c2][0], zf = z[1] + bg[c2][1];
        float zg = z[2] + bg[c2][2], zo = z[3] + bg[c2][3];
        float iv = 1.f / (1.f + __expf(-zi));
        float fv = 1.f / (1.f + __expf(-zf));
        float eg = __expf(2.f * zg);
        float gv = 1.f - 2.f / (eg + 1.f);
        float ov = 1.f / (1.f + __expf(-zo));
        float cn = fv * cst[c2] + iv * gv;
        cst[c2] = cn;
        float ec = __expf(2.f * cn);
        float th2 = 1.f - 2.f / (ec + 1.f);
        float hv = ov * th2;
        _Float16 hhv = (_Float16)hv;
        _Float16 hlv = (_Float16)(hv - (float)hhv);
        unsigned int pk = (unsigned int)f2b(hhv) | ((unsigned int)f2b(hlv) << 16);
        int dglob = cb * 8 + c2 * 4 + dd;
        __hip_atomic_store(hs2 + (size_t)((s + 1) & 1) * HS2_U32 + rowE * 512 + dglob, pk, RLX,
                           AGT);
      }
    }
    ARRIVE(s + 1);  // drain + publish h_s
    if (s < 511) {  // x-GEMM for s+1 runs in the barrier's propagation shadow
      f32x4 aN0 = Z, aN1 = Z;
      XGEMM(s + 1, aN0, aN1);
      aC0 = aN0;
      aC1 = aN1;
    }
  }

  // ---- epilogue: y_511 from h_511 (buffer 0), all blocks, distributed write ----
  if (WAIT(512)) return;
  {
    f16x8 hh[8], hl[8];
    const unsigned int* hp0 = hldA;  // buffer (512&1)==0
#pragma unroll
    for (int i = 0; i < 8; ++i) {
      const unsigned int* hp = hp0 + (kh * 8 + i) * 32;
      u64 u0 = __hip_atomic_load((const u64*)hp, RLX, AGT);
      u64 u1 = __hip_atomic_load((const u64*)(hp + 2), RLX, AGT);
      u64 u2 = __hip_atomic_load((const u64*)(hp + 16), RLX, AGT);
      u64 u3 = __hip_atomic_load((const u64*)(hp + 18), RLX, AGT);
      unsigned int wd[8] = {(unsigned int)u0, (unsigned int)(u0 >> 32),
                            (unsigned int)u1, (unsigned int)(u1 >> 32),
                            (unsigned int)u2, (unsigned int)(u2 >> 32),
                            (unsigned int)u3, (unsigned int)(u3 >> 32)};
#pragma unroll
      for (int j = 0; j < 8; ++j) {
        hh[i][j] = b2f((unsigned short)(wd[j] & 0xffffu));
        hl[i][j] = b2f((unsigned short)(wd[j] >> 16));
      }
    }
    f32x4 y0 = Z, y1 = Z, y2 = Z, y3 = Z;
#pragma unroll
    for (int i = 0; i < 8; ++i) {
      int ki = kh * 8 + i;
      const _Float16* ph0 = wlin_h + ((size_t)(0 * 16 + ki) * 64 + l) * 8;
      const _Float16* ph1 = wlin_h + ((size_t)(1 * 16 + ki) * 64 + l) * 8;
      const _Float16* ph2 = wlin_h + ((size_t)(2 * 16 + ki) * 64 + l) * 8;
      const _Float16* ph3 = wlin_h + ((size_t)(3 * 16 + ki) * 64 + l) * 8;
      f16x8 b0 = *(const f16x8*)ph0, b1 = *(const f16x8*)ph1;
      f16x8 b2 = *(const f16x8*)ph2, b3 = *(const f16x8*)ph3;
      y0 = MFMA16(hh[i], b0, y0);
      y1 = MFMA16(hh[i], b1, y1);
      y2 = MFMA16(hh[i], b2, y2);
      y3 = MFMA16(hh[i], b3, y3);
      y0 = MFMA16(hl[i], b0, y0);
      y1 = MFMA16(hl[i], b1, y1);
      y2 = MFMA16(hl[i], b2, y2);
      y3 = MFMA16(hl[i], b3, y3);
    }
    if (kh == 1) {
#pragma unroll
      for (int r = 0; r < 4; ++r) {
        scratch[((rtp * 4 + 0) * 4 + r) * 64 + l] = y0[r];
        scratch[((rtp * 4 + 1) * 4 + r) * 64 + l] = y1[r];
        scratch[((rtp * 4 + 2) * 4 + r) * 64 + l] = y2[r];
        scratch[((rtp * 4 + 3) * 4 + r) * 64 + l] = y3[r];
      }
    }
    __syncthreads();
    if (kh == 0) {
      float la0[4], la1[4], la2[4], la3[4];
#pragma unroll
      for (int r = 0; r < 4; ++r) {
        la0[r] = y0[r] + scratch[((rtp * 4 + 0) * 4 + r) * 64 + l] + blv0;
        la1[r] = y1[r] + scratch[((rtp * 4 + 1) * 4 + r) * 64 + l] + blv1;
        la2[r] = y2[r] + scratch[((rtp * 4 + 2) * 4 + r) * 64 + l] + blv2;
        la3[r] = y3[r] + scratch[((rtp * 4 + 3) * 4 + r) * 64 + l] + blv3;
      }
#pragma unroll
      for (int r = 0; r < 4; ++r) {
        float mx = fmaxf(fmaxf(la0[r], la1[r]), fmaxf(la2[r], la3[r]));
        mx = fmaxf(mx, __shfl_xor(mx, 1));
        mx = fmaxf(mx, __shfl_xor(mx, 2));
        mx = fmaxf(mx, __shfl_xor(mx, 4));
        mx = fmaxf(mx, __shfl_xor(mx, 8));
        float e0 = __expf(la0[r] - mx), e1 = __expf(la1[r] - mx);
        float e2 = __expf(la2[r] - mx), e3 = __expf(la3[r] - mx);
        float sm = e0 + e1 + e2 + e3;
        sm += __shfl_xor(sm, 1);
        sm += __shfl_xor(sm, 2);
        sm += __shfl_xor(sm, 4);
        sm += __shfl_xor(sm, 8);
        float inv = 1.f / sm;
        la0[r] = e0 * inv;
        la1[r] = e1 * inv;
        la2[r] = e2 * inv;
        la3[r] = e3 * inv;
      }
      if (l15 == lW) {
#pragma unroll
        for (int r = 0; r < 4; ++r) {
          float vv = (ctW == 0) ? la0[r] : (ctW == 1) ? la1[r] : (ctW == 2) ? la2[r] : la3[r];
          out[((size_t)(g * 64 + rtp * 16 + 4 * q + r) * 512 + 511) * 64 + cb] = vv;
        }
      }
    }
  }
}

extern "C" void kernel_launch(void* const* d_in, const int* in_sizes, int n_in, void* d_out,
                              int out_size, void* d_ws, size_t ws_size, hipStream_t stream) {
  const float* x = (const float*)d_in[0];
  const float* init_h = (const float*)d_in[1];
  const float* W_ih = (const float*)d_in[2];
  const float* b_ih = (const float*)d_in[3];
  const float* W_hh = (const float*)d_in[4];
  const float* b_hh = (const float*)d_in[5];
  const float* W_lin = (const float*)d_in[6];
  const float* b_lin = (const float*)d_in[7];
  float* out = (float*)d_out;
  (void)in_sizes;
  (void)n_in;
  (void)out_size;

  char* ws = (char*)d_ws;
  size_t off = 0;
  auto take = [&](size_t bytes) -> char* {
    char* r = ws + off;
    off = (off + bytes + 255) & ~(size_t)255;
    return r;
  };
  const size_t WFP_E = (size_t)128 * 34 * 64 * 8;   // gates weight f16 elems PER PLANE
  const size_t WLF_E = (size_t)4 * 16 * 64 * 8;     // W_lin hi frag f16 elems
  const size_t XS_E = (size_t)256 * 512 * 16 * 64;  // pre-split x f16 elems

  _Float16* wf_hi = (_Float16*)take(WFP_E * 2);
  _Float16* wf_lo = (_Float16*)take(WFP_E * 2);
  _Float16* wlf_hi = (_Float16*)take(WLF_E * 2);
  unsigned int* hs2 = (unsigned int*)take((size_t)2 * HS2_U32 * 4);
  float* bias = (float*)take(2048 * 4);
  int* flags = (int*)take((size_t)FLAG_INTS * 4);
  if (ws_size < off) return;  // cannot run -> visible failure
  _Float16* xs = (_Float16*)(ws + off);
  const bool xpre = (ws_size >= off + XS_E * 2);

  if (xpre) {
    const long total = 8388608L + 278528 + 4096 + 32768 + 2048 + FLAG_INTS;
    prep_kernel<true><<<(int)((total + 255) / 256), 256, 0, stream>>>(
        x, init_h, W_ih, b_ih, W_hh, b_hh, W_lin, xs, wf_hi, wf_lo, wlf_hi, hs2, bias, flags);
    recur_kernel<true><<<256, 512, 0, stream>>>(x, b_lin, xs, wf_hi, wf_lo, wlf_hi, hs2, bias,
                                                out, flags);
  } else {
    const long total = 278528L + 4096 + 32768 + 2048 + FLAG_INTS;
    prep_kernel<false><<<(int)((total + 255) / 256), 256, 0, stream>>>(
        x, init_h, W_ih, b_ih, W_hh, b_hh, W_lin, xs, wf_hi, wf_lo, wlf_hi, hs2, bias, flags);
    recur_kernel<false><<<256, 512, 0, stream>>>(x, b_lin, xs, wf_hi, wf_lo, wlf_hi, hs2, bias,
                                                 out, flags);
  }
}